// Round 11
// baseline (227.345 us; speedup 1.0000x reference)
//
#include <hip/hip_runtime.h>

#define L_NODES 100000
#define NFEAT   256
#define JDIM    128

typedef __bf16 bf16x8 __attribute__((ext_vector_type(8)));
typedef __bf16 bf16x4 __attribute__((ext_vector_type(4)));
typedef float  floatx4 __attribute__((ext_vector_type(4)));
typedef float  floatx2 __attribute__((ext_vector_type(2)));

// fp8 (OCP e4m3) pack/unpack via ISA ops (gfx940+).
__device__ inline floatx2 fp8x2_to_f32x2(unsigned int w) {   // decodes bits[15:0]
    floatx2 r;
    asm("v_cvt_pk_f32_fp8 %0, %1" : "=v"(r) : "v"(w));
    return r;
}
__device__ inline unsigned int f32x2_to_fp8x2(float a, float b) {  // pair in bits[15:0]
    unsigned int r;
    asm("v_cvt_pk_fp8_f32 %0, %1, %2" : "=v"(r) : "v"(a), "v"(b));
    return r;
}

// ---------------------------------------------------------------------------
// Prep:
//   WtH [128][256]: WtH[n][k]  = bf16(W_h1[k][n])
//   WtG2[256][128]: n<128: Wg[k][n] (U cols); n>=128: Wg[128+k][n-128] (V cols)
//     rows 128.. of WtG2 double as WtGv[n][k]=Wg[128+k][n] for k_gfinal.
// ---------------------------------------------------------------------------
__global__ __launch_bounds__(256) void k_prep(
    const float* __restrict__ Wh, const float* __restrict__ Wg,
    __bf16* __restrict__ WtH, __bf16* __restrict__ WtG2)
{
    int i = blockIdx.x * 256 + threadIdx.x;   // 32768
    int n = i >> 8, k = i & 255;
    WtH[i] = (__bf16)Wh[k * JDIM + n];
    int n2 = i >> 7, k2 = i & 127;
    WtG2[i] = (n2 < 128) ? (__bf16)Wg[k2 * JDIM + n2]
                         : (__bf16)Wg[(128 + k2) * JDIM + (n2 - 128)];
}

// ---------------------------------------------------------------------------
// Kernel 1 (fused h1+uv).  R22: staging split into TWO explicit 16-load
// batches (64-reg footprint each, R15-proven single-exposure shape) — the
// xa[32] version demanded 128 payload VGPRs against a 128-total allocation,
// forcing the compiler to chunk loads into small dependent groups (multiple
// exposed latencies).  Epilogue: U-bf16 store merged into the fp8 loop
// (halves redundant LDS re-reads).  Rest = R19/R21 structure.
// ---------------------------------------------------------------------------
__global__ __launch_bounds__(256, 2) void k_h1uv(
    const float* __restrict__ X, const __bf16* __restrict__ WtH,
    const __bf16* __restrict__ WtG2, const float* __restrict__ b,
    __bf16* __restrict__ U, unsigned char* __restrict__ U8,
    unsigned char* __restrict__ V8)
{
    __shared__ __bf16 Sm[128 * 264];  // As (stride 264) / Hs (stride 136) / Os

    const int tid  = threadIdx.x;
    const int row0 = blockIdx.x * 128;
    const int wave = tid >> 6, lane = tid & 63;
    const int lm = lane & 15, lq = lane >> 4;

    // ---- stage X tile: two batches of 16 fully-inflight NT loads ----
    {
        floatx4 xa[16];
        #pragma unroll
        for (int it = 0; it < 16; ++it) {
            int f4  = it * 256 + tid;                 // 0..4095
            int row = f4 >> 6, c4 = f4 & 63;
            int grow = row0 + row; if (grow >= L_NODES) grow = L_NODES - 1;
            xa[it] = __builtin_nontemporal_load(
                         reinterpret_cast<const floatx4*>(X + (size_t)grow * NFEAT + c4 * 4));
        }
        #pragma unroll
        for (int it = 0; it < 16; ++it) {
            int f4  = it * 256 + tid;
            int row = f4 >> 6, c4 = f4 & 63;
            bf16x4 o;
            o[0]=(__bf16)xa[it][0]; o[1]=(__bf16)xa[it][1];
            o[2]=(__bf16)xa[it][2]; o[3]=(__bf16)xa[it][3];
            *(bf16x4*)&Sm[row * 264 + c4 * 4] = o;
        }
    }
    {
        floatx4 xa[16];
        #pragma unroll
        for (int it = 0; it < 16; ++it) {
            int f4  = (16 + it) * 256 + tid;          // 4096..8191
            int row = f4 >> 6, c4 = f4 & 63;
            int grow = row0 + row; if (grow >= L_NODES) grow = L_NODES - 1;
            xa[it] = __builtin_nontemporal_load(
                         reinterpret_cast<const floatx4*>(X + (size_t)grow * NFEAT + c4 * 4));
        }
        #pragma unroll
        for (int it = 0; it < 16; ++it) {
            int f4  = (16 + it) * 256 + tid;
            int row = f4 >> 6, c4 = f4 & 63;
            bf16x4 o;
            o[0]=(__bf16)xa[it][0]; o[1]=(__bf16)xa[it][1];
            o[2]=(__bf16)xa[it][2]; o[3]=(__bf16)xa[it][3];
            *(bf16x4*)&Sm[row * 264 + c4 * 4] = o;
        }
    }

    // b1 panel (phase-1 only); latency hides under the barrier.
    bf16x8 b1[2][8];
    #pragma unroll
    for (int nt = 0; nt < 2; ++nt) {
        int ntg = wave * 2 + nt;
        #pragma unroll
        for (int ks = 0; ks < 8; ++ks)
            b1[nt][ks] = *(const bf16x8*)(WtH + (size_t)(ntg * 16 + lm) * 256 + ks * 32 + lq * 8);
    }
    __syncthreads();                                          // bar1: As ready

    // ---- phase 1: H = relu(X @ Wh + b), 128 rows ----
    floatx4 acc1[8][2] = {};
    #pragma unroll
    for (int ks = 0; ks < 8; ++ks) {
        bf16x8 af[8];
        #pragma unroll
        for (int t = 0; t < 8; ++t)
            af[t] = *(const bf16x8*)&Sm[(t * 16 + lm) * 264 + ks * 32 + lq * 8];
        #pragma unroll
        for (int t = 0; t < 8; ++t)
            #pragma unroll
            for (int nt = 0; nt < 2; ++nt)
                acc1[t][nt] = __builtin_amdgcn_mfma_f32_16x16x32_bf16(
                    af[t], b1[nt][ks], acc1[t][nt], 0, 0, 0);
    }
    __syncthreads();                                          // bar2: As reads closed

    // write Hs (stride 136; aliases As — As dead)
    #pragma unroll
    for (int nt = 0; nt < 2; ++nt) {
        int col = (wave * 2 + nt) * 16 + lm;
        float bias = b[col];
        #pragma unroll
        for (int t = 0; t < 8; ++t)
            #pragma unroll
            for (int p = 0; p < 4; ++p)
                Sm[(t * 16 + lq * 4 + p) * 136 + col] =
                    (__bf16)fmaxf(acc1[t][nt][p] + bias, 0.f);
    }
    __syncthreads();                                          // bar3: Hs ready

    // ---- phase 2: two ks-passes (h=0,1); both acc halves stay live ----
    floatx4 acc2a[8][2] = {}, acc2b[8][2] = {};
    {
        bf16x8 b2h[2][4];
        #pragma unroll
        for (int nt = 0; nt < 2; ++nt) {
            int ntg = wave * 4 + nt;                          // h = 0
            #pragma unroll
            for (int ks = 0; ks < 4; ++ks)
                b2h[nt][ks] = *(const bf16x8*)(WtG2 + (size_t)(ntg * 16 + lm) * 128 + ks * 32 + lq * 8);
        }
        #pragma unroll
        for (int ks = 0; ks < 4; ++ks) {
            bf16x8 af[8];
            #pragma unroll
            for (int t = 0; t < 8; ++t)
                af[t] = *(const bf16x8*)&Sm[(t * 16 + lm) * 136 + ks * 32 + lq * 8];
            #pragma unroll
            for (int t = 0; t < 8; ++t)
                #pragma unroll
                for (int nt = 0; nt < 2; ++nt)
                    acc2a[t][nt] = __builtin_amdgcn_mfma_f32_16x16x32_bf16(
                        af[t], b2h[nt][ks], acc2a[t][nt], 0, 0, 0);
        }
    }
    {
        bf16x8 b2h[2][4];
        #pragma unroll
        for (int nt = 0; nt < 2; ++nt) {
            int ntg = wave * 4 + 2 + nt;                      // h = 1
            #pragma unroll
            for (int ks = 0; ks < 4; ++ks)
                b2h[nt][ks] = *(const bf16x8*)(WtG2 + (size_t)(ntg * 16 + lm) * 128 + ks * 32 + lq * 8);
        }
        #pragma unroll
        for (int ks = 0; ks < 4; ++ks) {
            bf16x8 af[8];
            #pragma unroll
            for (int t = 0; t < 8; ++t)
                af[t] = *(const bf16x8*)&Sm[(t * 16 + lm) * 136 + ks * 32 + lq * 8];
            #pragma unroll
            for (int t = 0; t < 8; ++t)
                #pragma unroll
                for (int nt = 0; nt < 2; ++nt)
                    acc2b[t][nt] = __builtin_amdgcn_mfma_f32_16x16x32_bf16(
                        af[t], b2h[nt][ks], acc2b[t][nt], 0, 0, 0);
        }
    }
    __syncthreads();                                          // bar4: Hs reads closed

    // write Os (stride 264; aliases Hs — Hs dead); cols 0..127 = U, 128..255 = V
    #pragma unroll
    for (int h = 0; h < 2; ++h)
        #pragma unroll
        for (int nt = 0; nt < 2; ++nt) {
            int col = (wave * 4 + h * 2 + nt) * 16 + lm;
            #pragma unroll
            for (int t = 0; t < 8; ++t)
                #pragma unroll
                for (int p = 0; p < 4; ++p)
                    Sm[(t * 16 + lq * 4 + p) * 264 + col] =
                        (__bf16)(h ? acc2b[t][nt][p] : acc2a[t][nt][p]);
        }
    __syncthreads();                                          // bar5: Os ready

    // merged store: U bf16 + U8/V8 fp8, one pass over the Os tile
    #pragma unroll
    for (int it = 0; it < 16; ++it) {
        int fid = it * 256 + tid;                 // 0..4095
        int row = fid >> 5, c8 = fid & 31;
        int grow = row0 + row;
        if (grow < L_NODES) {
            int col = c8 * 8;
            bf16x8 v = *(bf16x8*)&Sm[row * 264 + col];
            unsigned int lo0 = f32x2_to_fp8x2((float)v[0], (float)v[1]);
            unsigned int hi0 = f32x2_to_fp8x2((float)v[2], (float)v[3]);
            unsigned int lo1 = f32x2_to_fp8x2((float)v[4], (float)v[5]);
            unsigned int hi1 = f32x2_to_fp8x2((float)v[6], (float)v[7]);
            uint2 o;
            o.x = (lo0 & 0xffffu) | (hi0 << 16);
            o.y = (lo1 & 0xffffu) | (hi1 << 16);
            if (col < 128) {
                *(bf16x8*)(U + (size_t)grow * JDIM + col) = v;
                *(uint2*)(U8 + (size_t)grow * JDIM + col) = o;
            } else {
                *(uint2*)(V8 + (size_t)grow * JDIM + (col - 128)) = o;
            }
        }
    }
}

// ---------------------------------------------------------------------------
// Kernel 2 (fused gather + final).  Unchanged from R21 (fp8 gather: 205 MB
// request volume, <59 us).  E2's direct U term stays bf16.
// ---------------------------------------------------------------------------
__global__ __launch_bounds__(256, 4) void k_gfinal(
    const __bf16* __restrict__ U, const unsigned char* __restrict__ U8,
    const unsigned char* __restrict__ V8,
    const __bf16* __restrict__ WtGv, const float* __restrict__ bg,
    const float* __restrict__ Wf, const float* __restrict__ bf,
    const int* __restrict__ idx0, const int* __restrict__ idx1,
    float* __restrict__ out)
{
    __shared__ int    sidx[2][8][64];               // 4 KB; part[] aliases this
    __shared__ __bf16 E1s[64 * 136];                // 17.4 KB
    __shared__ __bf16 Us [64 * 136];                // 17.4 KB
    float (*part)[64][2] = (float (*)[64][2])&sidx[0][0][0];   // 2 KB alias

    const int tid  = threadIdx.x;
    const int row0 = blockIdx.x * 64;
    const int wave = tid >> 6, lane = tid & 63;
    const int lm = lane & 15, lq = lane >> 4;

    // stage indices (1024 ints, 4/thread, NT) and U tile (4 bf16x8/thread)
    #pragma unroll
    for (int it = 0; it < 4; ++it) {
        int fid = it * 256 + tid;                 // 0..1023
        int m = fid >> 9, rem = fid & 511;
        int s = rem >> 6, il = rem & 63;
        int gr = row0 + il; if (gr >= L_NODES) gr = L_NODES - 1;
        const int* ip = (m ? idx1 : idx0) + (size_t)s * L_NODES + gr;
        sidx[m][s][il] = __builtin_nontemporal_load(ip);
    }
    #pragma unroll
    for (int it = 0; it < 4; ++it) {
        int fid = it * 256 + tid;                 // 0..1023
        int r = fid >> 4, c8 = fid & 15;
        int g = row0 + r; if (g >= L_NODES) g = L_NODES - 1;
        *(bf16x8*)&Us[r * 136 + c8 * 8] = *(const bf16x8*)(U + (size_t)g * JDIM + c8 * 8);
    }
    __syncthreads();

    // ---- phase A: fp8 gather-add into E1s (2-deep pipelined) ----
    {
        const int c0 = (tid & 15) * 8;            // col (and byte) chunk
        const int rb = tid >> 4;                  // row base 0..15 (+16k)
        float bias[8];
        *(float4*)&bias[0] = *(const float4*)(bg + c0);
        *(float4*)&bias[4] = *(const float4*)(bg + c0 + 4);

        float acc[4][8] = {};
        uint2 uA[4], vA[4], uB[4], vB[4];

        auto LOADP = [&](int s, uint2 (&uu)[4], uint2 (&vv)[4]) {
            #pragma unroll
            for (int rr = 0; rr < 4; ++rr) {
                int r = rb + rr * 16;
                int a0 = sidx[0][s][r], a1 = sidx[1][s][r];
                uu[rr] = *(const uint2*)(U8 + (size_t)a0 * JDIM + c0);
                vv[rr] = *(const uint2*)(V8 + (size_t)a1 * JDIM + c0);
            }
        };
        auto ACCUM = [&](uint2 (&uu)[4], uint2 (&vv)[4]) {
            #pragma unroll
            for (int rr = 0; rr < 4; ++rr) {
                floatx2 u0 = fp8x2_to_f32x2(uu[rr].x);
                floatx2 u1 = fp8x2_to_f32x2(uu[rr].x >> 16);
                floatx2 u2 = fp8x2_to_f32x2(uu[rr].y);
                floatx2 u3 = fp8x2_to_f32x2(uu[rr].y >> 16);
                floatx2 w0 = fp8x2_to_f32x2(vv[rr].x);
                floatx2 w1 = fp8x2_to_f32x2(vv[rr].x >> 16);
                floatx2 w2 = fp8x2_to_f32x2(vv[rr].y);
                floatx2 w3 = fp8x2_to_f32x2(vv[rr].y >> 16);
                acc[rr][0] += fmaxf(u0[0] + w0[0] + bias[0], 0.f);
                acc[rr][1] += fmaxf(u0[1] + w0[1] + bias[1], 0.f);
                acc[rr][2] += fmaxf(u1[0] + w1[0] + bias[2], 0.f);
                acc[rr][3] += fmaxf(u1[1] + w1[1] + bias[3], 0.f);
                acc[rr][4] += fmaxf(u2[0] + w2[0] + bias[4], 0.f);
                acc[rr][5] += fmaxf(u2[1] + w2[1] + bias[5], 0.f);
                acc[rr][6] += fmaxf(u3[0] + w3[0] + bias[6], 0.f);
                acc[rr][7] += fmaxf(u3[1] + w3[1] + bias[7], 0.f);
            }
        };

        LOADP(0, uA, vA);
        #pragma unroll
        for (int s = 0; s < 8; ++s) {
            if ((s & 1) == 0) {
                if (s < 7) LOADP(s + 1, uB, vB);
                ACCUM(uA, vA);
            } else {
                if (s < 7) LOADP(s + 1, uA, vA);
                ACCUM(uB, vB);
            }
        }

        #pragma unroll
        for (int rr = 0; rr < 4; ++rr) {
            int r = rb + rr * 16;
            bf16x8 o;
            #pragma unroll
            for (int p = 0; p < 8; ++p)
                o[p] = (__bf16)fmaxf(acc[rr][p] * 0.125f, 0.f);
            *(bf16x8*)&E1s[r * 136 + c0] = o;
        }
    }
    __syncthreads();   // also closes all sidx reads before part[] writes

    // B panel (phase-B-only): load now so it doesn't hold VGPRs in phase A
    bf16x8 b3[2][4];
    #pragma unroll
    for (int nt = 0; nt < 2; ++nt) {
        int ntg = wave * 2 + nt;
        #pragma unroll
        for (int ks = 0; ks < 4; ++ks)
            b3[nt][ks] = *(const bf16x8*)(WtGv + (size_t)(ntg * 16 + lm) * 128 + ks * 32 + lq * 8);
    }

    // ---- phase B: E2 = relu(U + E1 @ Wg_bot + bg); head ----
    floatx4 acc[4][2] = {};
    #pragma unroll
    for (int ks = 0; ks < 4; ++ks) {
        bf16x8 af[4];
        #pragma unroll
        for (int t = 0; t < 4; ++t)
            af[t] = *(const bf16x8*)&E1s[(t * 16 + lm) * 136 + ks * 32 + lq * 8];
        #pragma unroll
        for (int t = 0; t < 4; ++t)
            #pragma unroll
            for (int nt = 0; nt < 2; ++nt)
                acc[t][nt] = __builtin_amdgcn_mfma_f32_16x16x32_bf16(
                    af[t], b3[nt][ks], acc[t][nt], 0, 0, 0);
    }

    float bias[2], wf0[2], wf1[2];
    #pragma unroll
    for (int nt = 0; nt < 2; ++nt) {
        int col = (wave * 2 + nt) * 16 + lm;
        bias[nt] = bg[col];
        wf0[nt] = Wf[col * 2 + 0];
        wf1[nt] = Wf[col * 2 + 1];
    }
    #pragma unroll
    for (int t = 0; t < 4; ++t) {
        float p0[4], p1[4];
        #pragma unroll
        for (int p = 0; p < 4; ++p) {
            int r = t * 16 + lq * 4 + p;
            float a0 = 0.f, a1 = 0.f;
            #pragma unroll
            for (int nt = 0; nt < 2; ++nt) {
                int col = (wave * 2 + nt) * 16 + lm;
                float e2 = fmaxf((float)Us[r * 136 + col] + acc[t][nt][p] + bias[nt], 0.f);
                a0 = fmaf(e2, wf0[nt], a0);
                a1 = fmaf(e2, wf1[nt], a1);
            }
            p0[p] = a0; p1[p] = a1;
        }
        #pragma unroll
        for (int m = 1; m <= 8; m <<= 1)
            #pragma unroll
            for (int p = 0; p < 4; ++p) {
                p0[p] += __shfl_xor(p0[p], m, 16);
                p1[p] += __shfl_xor(p1[p], m, 16);
            }
        if (lm == 0)
            #pragma unroll
            for (int p = 0; p < 4; ++p) {
                part[wave][t * 16 + lq * 4 + p][0] = p0[p];
                part[wave][t * 16 + lq * 4 + p][1] = p1[p];
            }
    }
    __syncthreads();

    if (tid < 128) {
        int row = tid >> 1, o = tid & 1;
        int grow = row0 + row;
        if (grow < L_NODES) {
            float v = part[0][row][o] + part[1][row][o] + part[2][row][o]
                    + part[3][row][o] + bf[o];
            __builtin_nontemporal_store(v, &out[(size_t)grow * 2 + o]);
        }
    }
}

// ---------------------------------------------------------------------------
extern "C" void kernel_launch(void* const* d_in, const int* in_sizes, int n_in,
                              void* d_out, int out_size, void* d_ws, size_t ws_size,
                              hipStream_t stream) {
    const float* X    = (const float*)d_in[0];
    const float* W_h1 = (const float*)d_in[1];
    const float* b_h1 = (const float*)d_in[2];
    const float* W_g1 = (const float*)d_in[3];
    const float* b_g1 = (const float*)d_in[4];
    const float* W_f  = (const float*)d_in[5];
    const float* b_f  = (const float*)d_in[6];
    const int*   idx0 = (const int*)d_in[7];
    const int*   idx1 = (const int*)d_in[8];
    float* out = (float*)d_out;

    __bf16*        U   = (__bf16*)d_ws;                       // 25.6 MB
    unsigned char* U8  = (unsigned char*)(U + (size_t)L_NODES * JDIM);  // 12.8 MB
    unsigned char* V8  = U8 + (size_t)L_NODES * JDIM;         // 12.8 MB
    __bf16*        WtH = (__bf16*)(V8 + (size_t)L_NODES * JDIM);        // 64 KB
    __bf16*        WtG2 = WtH + 32768;                        // 64 KB
    __bf16*        WtGv = WtG2 + 128 * 128;                   // alias: rows 128..

    k_prep<<<128, 256, 0, stream>>>(W_h1, W_g1, WtH, WtG2);
    k_h1uv<<<(L_NODES + 127) / 128, 256, 0, stream>>>(X, WtH, WtG2, b_h1, U, U8, V8);
    k_gfinal<<<(L_NODES + 63) / 64, 256, 0, stream>>>(U, U8, V8, WtGv, b_g1, W_f, b_f,
                                                      idx0, idx1, out);
}